// Round 8
// baseline (888.425 us; speedup 1.0000x reference)
//
#include <hip/hip_runtime.h>

#define TT    512
#define BATCH 2048
#define DIN   64
#define HD    10
#define WROW  (DIN + HD)     // 74
#define NGATE 40             // 4 gates x 10 units
#define ZROW  40                                   // floats per (t,b) row of Z
#define ZSLAB ((size_t)BATCH * ZROW)               // floats per t-slab
#define ZNEED ((size_t)(TT + 4) * ZSLAB * 4)       // bytes incl. 4-deep prefetch pad

// ---------------- Kernel 1: Z[(t*B+b)*40 + u*4+g] = X[t,b,:] . W_g[u,:] + b_g[u] ----
// R5-proven LDS-broadcast structure; only the store column is permuted to
// unit-major (u*4+g) so the rec kernel reads one float4 per unit.
__global__ __launch_bounds__(256, 2)
void zgemm_kernel(const float* __restrict__ X,
                  const float* __restrict__ Wf, const float* __restrict__ bf,
                  const float* __restrict__ Wi, const float* __restrict__ bi,
                  const float* __restrict__ Wu, const float* __restrict__ bu,
                  const float* __restrict__ Wo, const float* __restrict__ bo,
                  float* __restrict__ Z)
{
    const int tid  = threadIdx.x;
    const int n    = tid & 63;          // output column (only n<40 real)
    const int msub = tid >> 6;          // wave id 0..3
    __shared__ float xs[16][64];

    float w[DIN];
    float bias = 0.f;
    int zcol = 0;
    {
        const float* Wg = Wf; const float* bg = bf;
        const int g = n / HD;
        if (g == 1) { Wg = Wi; bg = bi; }
        else if (g == 2) { Wg = Wu; bg = bu; }
        else if (g == 3) { Wg = Wo; bg = bo; }
        const int q = n - g * HD;
        if (n < NGATE) {
            #pragma unroll
            for (int k = 0; k < DIN; ++k) w[k] = Wg[q * WROW + k];
            bias = bg[q];
            zcol = q * 4 + g;           // unit-major column
        } else {
            #pragma unroll
            for (int k = 0; k < DIN; ++k) w[k] = 0.f;
        }
    }

    const size_t m0 = (size_t)blockIdx.x * 64;      // 64 rows per block
    #pragma unroll 1
    for (int c = 0; c < 4; ++c) {
        const size_t mc = m0 + (size_t)c * 16;
        __syncthreads();
        // stage 16 rows (1024 floats) coalesced: thread -> float4 at flat offset 4*tid
        {
            const float4 xv = *reinterpret_cast<const float4*>(&X[mc * DIN + (size_t)tid * 4]);
            *reinterpret_cast<float4*>(&xs[0][0] + tid * 4) = xv;
        }
        __syncthreads();
        #pragma unroll
        for (int j = 0; j < 4; ++j) {
            const int ml = msub * 4 + j;            // row within chunk (uniform per wave)
            float s0 = bias, s1 = 0.f, s2 = 0.f, s3 = 0.f;
            #pragma unroll
            for (int k = 0; k < DIN; k += 4) {
                float4 xq = *reinterpret_cast<const float4*>(&xs[ml][k]);  // broadcast
                s0 = fmaf(w[k + 0], xq.x, s0);
                s1 = fmaf(w[k + 1], xq.y, s1);
                s2 = fmaf(w[k + 2], xq.z, s2);
                s3 = fmaf(w[k + 3], xq.w, s3);
            }
            if (n < NGATE) Z[(mc + ml) * ZROW + zcol] = (s0 + s1) + (s2 + s3);
        }
    }
}

// ---------------- Kernel 2 (v3): all-gates-per-lane recurrence ----------------
// One wave per batch row. Lane v = lane&15 owns unit uw = 15-v for the z/cos side
// (reversed so flip(cumprod) = DPP row_shl suffix product); the scan result for
// unit q = v-6 lands on the same lane, and f,i,u,o are ALL computed in-lane:
// no cross-lane gather remains in the chain. One float4 Z load per step (4-deep
// named prefetch). The _fcl modulation m is deferred: h = m*hpre, so the next
// z-dot uses hpre (available early) and multiplies by m once.
__global__ __launch_bounds__(64, 2)
void qlstm_rec_kernel(const float* __restrict__ Z,
                      const float* __restrict__ Wf, const float* __restrict__ Wi,
                      const float* __restrict__ Wu, const float* __restrict__ Wo,
                      float* __restrict__ out)
{
    const int row  = blockIdx.x;
    const int lane = threadIdx.x;
    const int v    = lane & 15;
    int uw = 15 - v; if (uw > 9) uw = 9;     // dummy lanes (v<6) clamp

    const float LOG2E  = 1.4426950408889634f;
    const float INV2PI = 0.15915494309189535f;

    // per-lane h-weights for all 4 gates of unit uw
    float whf[HD], whi[HD], whu[HD], who[HD];
    #pragma unroll
    for (int j = 0; j < HD; ++j) {
        whf[j] = Wf[uw * WROW + DIN + j];
        whi[j] = Wi[uw * WROW + DIN + j];
        whu[j] = Wu[uw * WROW + DIN + j];
        who[j] = Wo[uw * WROW + DIN + j];
    }

    const float4* Zp = reinterpret_cast<const float4*>(
        Z + (size_t)row * ZROW + (size_t)uw * 4);
    const size_t ZS4 = (size_t)BATCH * (ZROW / 4);   // float4 stride per t-slab

    float h[HD];                   // replicated hpre (uniform via readlane)
    #pragma unroll
    for (int j = 0; j < HD; ++j) h[j] = 0.f;
    float c = 0.f, m = 1.f, hkeep = 0.f;

    float* op = out + (size_t)row * HD + (lane - 6);

    // 4 named in-flight float4 Z registers
    float4 za = Zp[0];
    float4 zb = Zp[ZS4];
    float4 zc = Zp[2 * ZS4];
    float4 zd = Zp[3 * ZS4];

#define QSTEP(ZQ, TNEXT)                                                                \
    {                                                                                   \
        const float4 zq = ZQ;                                                           \
        ZQ = Zp[(size_t)(TNEXT) * ZS4];                  /* prefetch 4 ahead */         \
        float zhf = 0.f, zhi = 0.f, zhu = 0.f, zho = 0.f;                               \
        _Pragma("unroll")                                                               \
        for (int j = 0; j < HD; ++j) {                                                  \
            zhf = fmaf(whf[j], h[j], zhf);                                              \
            zhi = fmaf(whi[j], h[j], zhi);                                              \
            zhu = fmaf(whu[j], h[j], zhu);                                              \
            zho = fmaf(who[j], h[j], zho);                                              \
        }                                                                               \
        float zf = fmaf(m, zhf, zq.x);                                                  \
        float zi = fmaf(m, zhi, zq.y);                                                  \
        float zu = fmaf(m, zhu, zq.z);                                                  \
        float zo = fmaf(m, zho, zq.w);                                                  \
        zf = fminf(fmaxf(zf, -5.f), 5.f);                                               \
        zi = fminf(fmaxf(zi, -5.f), 5.f);                                               \
        zu = fminf(fmaxf(zu, -5.f), 5.f);                                               \
        zo = fminf(fmaxf(zo, -5.f), 5.f);                                               \
        float pf = __builtin_amdgcn_cosf(zf * INV2PI);                                  \
        float pi_ = __builtin_amdgcn_cosf(zi * INV2PI);                                 \
        float pu = __builtin_amdgcn_cosf(zu * INV2PI);                                  \
        float po = __builtin_amdgcn_cosf(zo * INV2PI);                                  \
        int s_;                                                                         \
        s_ = __builtin_amdgcn_update_dpp(0x3f800000, __float_as_int(pf), 0x101, 0xF, 0xF, false); pf *= __int_as_float(s_); \
        s_ = __builtin_amdgcn_update_dpp(0x3f800000, __float_as_int(pi_), 0x101, 0xF, 0xF, false); pi_ *= __int_as_float(s_); \
        s_ = __builtin_amdgcn_update_dpp(0x3f800000, __float_as_int(pu), 0x101, 0xF, 0xF, false); pu *= __int_as_float(s_); \
        s_ = __builtin_amdgcn_update_dpp(0x3f800000, __float_as_int(po), 0x101, 0xF, 0xF, false); po *= __int_as_float(s_); \
        s_ = __builtin_amdgcn_update_dpp(0x3f800000, __float_as_int(pf), 0x102, 0xF, 0xF, false); pf *= __int_as_float(s_); \
        s_ = __builtin_amdgcn_update_dpp(0x3f800000, __float_as_int(pi_), 0x102, 0xF, 0xF, false); pi_ *= __int_as_float(s_); \
        s_ = __builtin_amdgcn_update_dpp(0x3f800000, __float_as_int(pu), 0x102, 0xF, 0xF, false); pu *= __int_as_float(s_); \
        s_ = __builtin_amdgcn_update_dpp(0x3f800000, __float_as_int(po), 0x102, 0xF, 0xF, false); po *= __int_as_float(s_); \
        s_ = __builtin_amdgcn_update_dpp(0x3f800000, __float_as_int(pf), 0x104, 0xF, 0xF, false); pf *= __int_as_float(s_); \
        s_ = __builtin_amdgcn_update_dpp(0x3f800000, __float_as_int(pi_), 0x104, 0xF, 0xF, false); pi_ *= __int_as_float(s_); \
        s_ = __builtin_amdgcn_update_dpp(0x3f800000, __float_as_int(pu), 0x104, 0xF, 0xF, false); pu *= __int_as_float(s_); \
        s_ = __builtin_amdgcn_update_dpp(0x3f800000, __float_as_int(po), 0x104, 0xF, 0xF, false); po *= __int_as_float(s_); \
        s_ = __builtin_amdgcn_update_dpp(0x3f800000, __float_as_int(pf), 0x108, 0xF, 0xF, false); pf *= __int_as_float(s_); \
        s_ = __builtin_amdgcn_update_dpp(0x3f800000, __float_as_int(pi_), 0x108, 0xF, 0xF, false); pi_ *= __int_as_float(s_); \
        s_ = __builtin_amdgcn_update_dpp(0x3f800000, __float_as_int(pu), 0x108, 0xF, 0xF, false); pu *= __int_as_float(s_); \
        s_ = __builtin_amdgcn_update_dpp(0x3f800000, __float_as_int(po), 0x108, 0xF, 0xF, false); po *= __int_as_float(s_); \
        /* activations: sigmoid for f,i,o ; tanh for u */                               \
        float ef = __builtin_amdgcn_exp2f(-LOG2E * pf);                                 \
        float ei = __builtin_amdgcn_exp2f(-LOG2E * pi_);                                \
        float eu = __builtin_amdgcn_exp2f(-2.f * LOG2E * pu);                           \
        float eo = __builtin_amdgcn_exp2f(-LOG2E * po);                                 \
        float gf = __builtin_amdgcn_rcpf(1.f + ef);                                     \
        float gi = __builtin_amdgcn_rcpf(1.f + ei);                                     \
        float gu = 2.f * __builtin_amdgcn_rcpf(1.f + eu) - 1.f;                         \
        float go = __builtin_amdgcn_rcpf(1.f + eo);                                     \
        c = fmaf(gf, c, gi * gu);                                                       \
        float e2 = __builtin_amdgcn_exp2f(-2.f * LOG2E * c);                            \
        float th = 2.f * __builtin_amdgcn_rcpf(1.f + e2) - 1.f;                         \
        float hpre = go * th;                                                           \
        _Pragma("unroll")                                                               \
        for (int j = 0; j < HD; ++j)                                                    \
            h[j] = __int_as_float(__builtin_amdgcn_readlane(__float_as_int(hpre), 6 + j)); \
        m = __builtin_amdgcn_cosf(h[9] * INV2PI);                                       \
        float hst = m * hpre;                                                           \
        hkeep = hst;                                                                    \
        if (lane >= 6 && lane < 16) *op = hst;                                          \
        op += (size_t)BATCH * HD;                                                       \
    }

    #pragma unroll 1
    for (int t = 0; t < TT; t += 4) {
        QSTEP(za, t + 4)
        QSTEP(zb, t + 5)
        QSTEP(zc, t + 6)
        QSTEP(zd, t + 7)
    }
#undef QSTEP

    if (lane >= 6 && lane < 16) {
        const size_t base = (size_t)TT * BATCH * HD;
        out[base + (size_t)row * HD + (lane - 6)] = hkeep;
        out[base + (size_t)BATCH * HD + (size_t)row * HD + (lane - 6)] = c;
    }
}

// ---------------- Fallback: R3 fused kernel (used only if ws too small) ----------------
__global__ __launch_bounds__(64, 2)
void qlstm_fused_kernel(const float* __restrict__ X,
                        const float* __restrict__ Wf, const float* __restrict__ bf,
                        const float* __restrict__ Wi, const float* __restrict__ bi,
                        const float* __restrict__ Wu, const float* __restrict__ bu,
                        const float* __restrict__ Wo, const float* __restrict__ bo,
                        float* __restrict__ out)
{
    const int row  = blockIdx.x;
    const int lane = threadIdx.x;
    const int g    = lane >> 4;
    const int v    = lane & 15;
    const bool act_lane = (v >= 6);

    __shared__ float xs[2][DIN];

    const float LOG2E  = 1.4426950408889634f;
    const float INV2PI = 0.15915494309189535f;

    float cmul = -LOG2E, amul = 1.f, aadd = 0.f;
    const float* Wg = Wf; const float* bg = bf;
    if (g == 1) { Wg = Wi; bg = bi; }
    else if (g == 2) { Wg = Wu; bg = bu; cmul = -2.f * LOG2E; amul = 2.f; aadd = -1.f; }
    else if (g == 3) { Wg = Wo; bg = bo; }

    float wx[DIN];
    float wh[HD];
    float bias = 0.f;
    if (act_lane) {
        const int uw = 15 - v;
        #pragma unroll
        for (int k = 0; k < DIN; ++k) wx[k] = Wg[uw * WROW + k];
        #pragma unroll
        for (int k = 0; k < HD; ++k)  wh[k] = Wg[uw * WROW + DIN + k];
        bias = bg[uw];
    } else {
        #pragma unroll
        for (int k = 0; k < DIN; ++k) wx[k] = 0.f;
        #pragma unroll
        for (int k = 0; k < HD; ++k)  wh[k] = 0.f;
    }

    float h[HD];
    #pragma unroll
    for (int k = 0; k < HD; ++k) h[k] = 0.f;
    float c = 0.f;
    float hkeep = 0.f;

    const size_t xstep = (size_t)BATCH * DIN;
    const size_t xbase = (size_t)row * DIN + lane;

    xs[0][lane] = X[xbase];
    float xr = X[xstep + xbase];

    float zx;
    {
        float s0 = bias, s1 = 0.f, s2 = 0.f, s3 = 0.f;
        #pragma unroll
        for (int k = 0; k < DIN; k += 4) {
            float4 xq = *reinterpret_cast<const float4*>(&xs[0][k]);
            s0 = fmaf(wx[k + 0], xq.x, s0);
            s1 = fmaf(wx[k + 1], xq.y, s1);
            s2 = fmaf(wx[k + 2], xq.z, s2);
            s3 = fmaf(wx[k + 3], xq.w, s3);
        }
        zx = (s0 + s1) + (s2 + s3);
    }

    int cur = 0;
    for (int t = 0; t < TT; ++t) {
        const int nxt = cur ^ 1;
        if (t + 1 < TT) xs[nxt][lane] = xr;
        if (t + 2 < TT) xr = X[(size_t)(t + 2) * xstep + xbase];

        float za = zx, zb = 0.f;
        #pragma unroll
        for (int j = 0; j < HD; j += 2) {
            za = fmaf(wh[j],     h[j],     za);
            zb = fmaf(wh[j + 1], h[j + 1], zb);
        }
        float z = za + zb;
        z = fminf(fmaxf(z, -5.f), 5.f);
        float p = __builtin_amdgcn_cosf(z * INV2PI);

        {
            int s_;
            s_ = __builtin_amdgcn_update_dpp(0x3f800000, __float_as_int(p), 0x101, 0xF, 0xF, false);
            p *= __int_as_float(s_);
            s_ = __builtin_amdgcn_update_dpp(0x3f800000, __float_as_int(p), 0x102, 0xF, 0xF, false);
            p *= __int_as_float(s_);
            s_ = __builtin_amdgcn_update_dpp(0x3f800000, __float_as_int(p), 0x104, 0xF, 0xF, false);
            p *= __int_as_float(s_);
            s_ = __builtin_amdgcn_update_dpp(0x3f800000, __float_as_int(p), 0x108, 0xF, 0xF, false);
            p *= __int_as_float(s_);
        }

        float e = __builtin_amdgcn_exp2f(cmul * p);
        float a = amul * __builtin_amdgcn_rcpf(1.f + e) + aadd;

        float fg = __shfl(a, v);
        float ig = __shfl(a, 16 + v);
        float ug = __shfl(a, 32 + v);
        float og = __shfl(a, 48 + v);

        c = fmaf(fg, c, ig * ug);
        float e2 = __builtin_amdgcn_exp2f(-2.f * LOG2E * c);
        float th = 2.f * __builtin_amdgcn_rcpf(1.f + e2) - 1.f;
        float hpre = og * th;
        float h9 = __int_as_float(__builtin_amdgcn_readlane(__float_as_int(hpre), 15));
        float m = __builtin_amdgcn_cosf(h9 * INV2PI);
        float hnew = hpre * m;
        hkeep = hnew;

        if (lane >= 6 && lane < 16) out[((size_t)t * BATCH + row) * HD + (lane - 6)] = hnew;

        #pragma unroll
        for (int j = 0; j < HD; ++j)
            h[j] = __int_as_float(__builtin_amdgcn_readlane(__float_as_int(hnew), 6 + j));

        if (t + 1 < TT) {
            float s0 = bias, s1 = 0.f, s2 = 0.f, s3 = 0.f;
            const float* xp = xs[nxt];
            #pragma unroll
            for (int k = 0; k < DIN; k += 4) {
                float4 xq = *reinterpret_cast<const float4*>(&xp[k]);
                s0 = fmaf(wx[k + 0], xq.x, s0);
                s1 = fmaf(wx[k + 1], xq.y, s1);
                s2 = fmaf(wx[k + 2], xq.z, s2);
                s3 = fmaf(wx[k + 3], xq.w, s3);
            }
            zx = (s0 + s1) + (s2 + s3);
        }
        cur = nxt;
    }

    if (lane >= 6 && lane < 16) {
        const size_t base = (size_t)TT * BATCH * HD;
        out[base + (size_t)row * HD + (lane - 6)] = hkeep;
        out[base + (size_t)BATCH * HD + (size_t)row * HD + (lane - 6)] = c;
    }
}

extern "C" void kernel_launch(void* const* d_in, const int* in_sizes, int n_in,
                              void* d_out, int out_size, void* d_ws, size_t ws_size,
                              hipStream_t stream) {
    const float* X  = (const float*)d_in[0];
    const float* Wf = (const float*)d_in[1];
    const float* bf = (const float*)d_in[2];
    const float* Wi = (const float*)d_in[3];
    const float* bi = (const float*)d_in[4];
    const float* Wu = (const float*)d_in[5];
    const float* bu = (const float*)d_in[6];
    const float* Wo = (const float*)d_in[7];
    const float* bo = (const float*)d_in[8];
    float* out = (float*)d_out;

    if (ws_size >= ZNEED) {
        float* Zbuf = (float*)d_ws;
        zgemm_kernel<<<(TT * BATCH) / 64, 256, 0, stream>>>(
            X, Wf, bf, Wi, bi, Wu, bu, Wo, bo, Zbuf);
        qlstm_rec_kernel<<<BATCH, 64, 0, stream>>>(Zbuf, Wf, Wi, Wu, Wo, out);
    } else {
        qlstm_fused_kernel<<<BATCH, 64, 0, stream>>>(
            X, Wf, bf, Wi, bi, Wu, bu, Wo, bo, out);
    }
}